// Round 3
// baseline (1361.378 us; speedup 1.0000x reference)
//
#include <hip/hip_runtime.h>
#include <cstddef>

static constexpr int NN = 100000;   // nodes
static constexpr int NE = 1600000;  // edges
static constexpr int D  = 64;
static constexpr int H  = 128;
static constexpr int O  = 64;
static constexpr int TILE = 1024;
static constexpr int NT = (NN + TILE - 1) / TILE;   // 98 scan tiles

// ---------------- CSR construction ----------------

__global__ void zero_i32(int* p, int n) {
    int i = blockIdx.x * blockDim.x + threadIdx.x;
    if (i < n) p[i] = 0;
}

// edge_index layout: src = eidx[0..NE), dst = eidx[NE..2NE)  (int32 per harness)
__global__ void hist_kernel(const int* __restrict__ eidx, int* __restrict__ counts) {
    int e = blockIdx.x * blockDim.x + threadIdx.x;
    if (e < NE) atomicAdd(&counts[eidx[NE + e]], 1);
}

__global__ void scan_phaseA(const int* __restrict__ counts, int* __restrict__ bsum) {
    __shared__ int s[256];
    int t = threadIdx.x, b = blockIdx.x;
    int base = b * TILE + t * 4;
    int acc = 0;
#pragma unroll
    for (int j = 0; j < 4; j++) { int i = base + j; if (i < NN) acc += counts[i]; }
    s[t] = acc; __syncthreads();
    for (int off = 128; off > 0; off >>= 1) {
        if (t < off) s[t] += s[t + off];
        __syncthreads();
    }
    if (t == 0) bsum[b] = s[0];
}

__global__ void scan_phaseB(const int* __restrict__ bsum, int* __restrict__ boff,
                            int* __restrict__ row_ptr) {
    __shared__ int s[128];
    int t = threadIdx.x;
    int v = (t < NT) ? bsum[t] : 0;
    s[t] = v; __syncthreads();
    for (int off = 1; off < 128; off <<= 1) {
        int x = (t >= off) ? s[t - off] : 0;
        __syncthreads();
        s[t] += x;
        __syncthreads();
    }
    boff[t] = s[t] - v;                 // exclusive
    if (t == 127) row_ptr[NN] = s[127]; // total == NE
}

__global__ void scan_phaseC(const int* __restrict__ counts, const int* __restrict__ boff,
                            int* __restrict__ row_ptr, int* __restrict__ cursor) {
    __shared__ int s[256];
    int t = threadIdx.x, b = blockIdx.x;
    int base = b * TILE + t * 4;
    int v[4];
#pragma unroll
    for (int j = 0; j < 4; j++) { int i = base + j; v[j] = (i < NN) ? counts[i] : 0; }
    int tsum = v[0] + v[1] + v[2] + v[3];
    s[t] = tsum; __syncthreads();
    for (int off = 1; off < 256; off <<= 1) {
        int x = (t >= off) ? s[t - off] : 0;
        __syncthreads();
        s[t] += x;
        __syncthreads();
    }
    int pre = boff[b] + s[t] - tsum;    // exclusive prefix for this thread's first elem
#pragma unroll
    for (int j = 0; j < 4; j++) {
        int i = base + j;
        if (i < NN) { row_ptr[i] = pre; cursor[i] = pre; }
        pre += v[j];
    }
}

__global__ void fill_kernel(const int* __restrict__ eidx, int* __restrict__ cursor,
                            int* __restrict__ ecsr) {
    int e = blockIdx.x * blockDim.x + threadIdx.x;
    if (e < NE) {
        int d = eidx[NE + e];
        int pos = atomicAdd(&cursor[d], 1);
        ecsr[pos] = eidx[e];   // store src
    }
}

// ---------------- mean aggregation (gather via CSR) ----------------
// float4 per lane: F/4 threads per node. Edge loop unrolled x4 with independent
// accumulators -> 4 outstanding 16B gathers per lane (latency -> BW bound).
template<int F>
__launch_bounds__(256)
__global__ void aggregate_kernel(const float* __restrict__ feat, const int* __restrict__ row_ptr,
                                 const int* __restrict__ ecsr, float* __restrict__ meanout) {
    constexpr int TPN = F / 4;        // threads per node
    constexpr int NPB = 256 / TPN;    // nodes per block
    int node = blockIdx.x * NPB + threadIdx.x / TPN;
    int lane = threadIdx.x % TPN;
    if (node >= NN) return;
    int beg = row_ptr[node], end = row_ptr[node + 1];
    const float4* frow = (const float4*)feat;

    float4 a0 = make_float4(0.f, 0.f, 0.f, 0.f);
    float4 a1 = a0, a2 = a0, a3 = a0;

    int i = beg;
    for (; i + 4 <= end; i += 4) {
        int s0 = ecsr[i + 0], s1 = ecsr[i + 1], s2 = ecsr[i + 2], s3 = ecsr[i + 3];
        float4 v0 = frow[(size_t)s0 * TPN + lane];
        float4 v1 = frow[(size_t)s1 * TPN + lane];
        float4 v2 = frow[(size_t)s2 * TPN + lane];
        float4 v3 = frow[(size_t)s3 * TPN + lane];
        a0.x += v0.x; a0.y += v0.y; a0.z += v0.z; a0.w += v0.w;
        a1.x += v1.x; a1.y += v1.y; a1.z += v1.z; a1.w += v1.w;
        a2.x += v2.x; a2.y += v2.y; a2.z += v2.z; a2.w += v2.w;
        a3.x += v3.x; a3.y += v3.y; a3.z += v3.z; a3.w += v3.w;
    }
    for (; i < end; i++) {
        int s0 = ecsr[i];
        float4 v0 = frow[(size_t)s0 * TPN + lane];
        a0.x += v0.x; a0.y += v0.y; a0.z += v0.z; a0.w += v0.w;
    }
    a0.x += a1.x + a2.x + a3.x;
    a0.y += a1.y + a2.y + a3.y;
    a0.z += a1.z + a2.z + a3.z;
    a0.w += a1.w + a2.w + a3.w;

    int deg = end - beg;
    float r = (deg > 0) ? 1.f / (float)deg : 0.f;
    float4 o = make_float4(a0.x * r, a0.y * r, a0.z * r, a0.w * r);
    ((float4*)meanout)[(size_t)node * TPN + lane] = o;
}

// ---------------- fused fp32 GEMM:  out = [relu]( A1@W1 [+ A2@W2] + bias ) ----------------
// A: [NN x K] row-major, W: [K x C] row-major, out: [NN x C].
// TM=32 rows/block: dual-128 LDS = 33.8KB -> 4 blocks/CU (vs 2 at TM=64),
// occupancy 18% -> ~50% theoretical; VALU latency hiding was the bottleneck.
template<int K, int C, bool DUAL, bool RELU>
__launch_bounds__(256)
__global__ void gemm_fused(const float* __restrict__ A1, const float* __restrict__ W1,
                           const float* __restrict__ A2, const float* __restrict__ W2,
                           const float* __restrict__ bias, float* __restrict__ out) {
    constexpr int TM  = 32;
    constexpr int KP  = K + 4;          // padded LDS row stride (keeps 16B align)
    constexpr int CG  = C / 4;          // col groups (float4 per thread)
    constexpr int RG  = 256 / CG;       // row-thread groups
    constexpr int RPT = TM / RG;        // rows per thread
    __shared__ float As1[TM * KP];
    __shared__ float As2[DUAL ? TM * KP : 4];

    const int tid  = threadIdx.x;
    const int row0 = blockIdx.x * TM;

    constexpr int NV = TM * K / 4;      // float4 count of one A tile
    for (int v = tid; v < NV; v += 256) {
        int e = v * 4; int r = e / K; int k = e % K;
        int gr = row0 + r;
        float4 a = (gr < NN) ? *(const float4*)&A1[(size_t)gr * K + k]
                             : make_float4(0.f, 0.f, 0.f, 0.f);
        *(float4*)&As1[r * KP + k] = a;
        if constexpr (DUAL) {
            float4 a2 = (gr < NN) ? *(const float4*)&A2[(size_t)gr * K + k]
                                  : make_float4(0.f, 0.f, 0.f, 0.f);
            *(float4*)&As2[r * KP + k] = a2;
        }
    }
    __syncthreads();

    const int tx = tid % CG, ty = tid / CG;
    const int c0 = tx * 4;
    const int rbase = ty * RPT;

    float acc[RPT][4];
    {
        float4 b4 = *(const float4*)&bias[c0];
#pragma unroll
        for (int i = 0; i < RPT; i++) {
            acc[i][0] = b4.x; acc[i][1] = b4.y; acc[i][2] = b4.z; acc[i][3] = b4.w;
        }
    }

    for (int k = 0; k < K; k += 4) {
        float w1[4][4];
#pragma unroll
        for (int kk = 0; kk < 4; kk++) {
            float4 t = *(const float4*)&W1[(size_t)(k + kk) * C + c0];
            w1[kk][0] = t.x; w1[kk][1] = t.y; w1[kk][2] = t.z; w1[kk][3] = t.w;
        }
#pragma unroll
        for (int i = 0; i < RPT; i++) {
            float4 a = *(const float4*)&As1[(rbase + i) * KP + k];
#pragma unroll
            for (int j = 0; j < 4; j++)
                acc[i][j] += a.x * w1[0][j] + a.y * w1[1][j] + a.z * w1[2][j] + a.w * w1[3][j];
        }
        if constexpr (DUAL) {
            float w2[4][4];
#pragma unroll
            for (int kk = 0; kk < 4; kk++) {
                float4 t = *(const float4*)&W2[(size_t)(k + kk) * C + c0];
                w2[kk][0] = t.x; w2[kk][1] = t.y; w2[kk][2] = t.z; w2[kk][3] = t.w;
            }
#pragma unroll
            for (int i = 0; i < RPT; i++) {
                float4 a = *(const float4*)&As2[(rbase + i) * KP + k];
#pragma unroll
                for (int j = 0; j < 4; j++)
                    acc[i][j] += a.x * w2[0][j] + a.y * w2[1][j] + a.z * w2[2][j] + a.w * w2[3][j];
            }
        }
    }

#pragma unroll
    for (int i = 0; i < RPT; i++) {
        int gr = row0 + rbase + i;
        if (gr < NN) {
            float4 o;
            o.x = RELU ? fmaxf(acc[i][0], 0.f) : acc[i][0];
            o.y = RELU ? fmaxf(acc[i][1], 0.f) : acc[i][1];
            o.z = RELU ? fmaxf(acc[i][2], 0.f) : acc[i][2];
            o.w = RELU ? fmaxf(acc[i][3], 0.f) : acc[i][3];
            *(float4*)&out[(size_t)gr * C + c0] = o;
        }
    }
}

// ---------------- launch ----------------

extern "C" void kernel_launch(void* const* d_in, const int* in_sizes, int n_in,
                              void* d_out, int out_size, void* d_ws, size_t ws_size,
                              hipStream_t stream) {
    const float* x     = (const float*)d_in[0];
    const int*   eidx  = (const int*)d_in[1];
    const float* W1l   = (const float*)d_in[2];
    const float* b1    = (const float*)d_in[3];
    const float* W1r   = (const float*)d_in[4];
    const float* Wlin1 = (const float*)d_in[5];
    const float* blin1 = (const float*)d_in[6];
    const float* W2l   = (const float*)d_in[7];
    const float* b2    = (const float*)d_in[8];
    const float* W2r   = (const float*)d_in[9];
    const float* Wlin2 = (const float*)d_in[10];
    const float* blin2 = (const float*)d_in[11];
    float* out = (float*)d_out;
    (void)in_sizes; (void)n_in; (void)out_size; (void)ws_size;

    char* ws = (char*)d_ws;
    size_t off = 0;
    auto alloc = [&](size_t bytes) -> void* {
        void* p = ws + off;
        off = (off + bytes + 255) & ~(size_t)255;
        return p;
    };
    int*   counts  = (int*)alloc((size_t)NN * 4);
    int*   bsum    = (int*)alloc(128 * 4);
    int*   boff    = (int*)alloc(128 * 4);
    int*   row_ptr = (int*)alloc((size_t)(NN + 1) * 4);
    int*   cursor  = (int*)alloc((size_t)NN * 4);
    int*   ecsr    = (int*)alloc((size_t)NE * 4);
    float* bufA    = (float*)alloc((size_t)NN * H * 4);
    float* bufB    = (float*)alloc((size_t)NN * H * 4);
    float* bufC    = (float*)alloc((size_t)NN * H * 4);

    // CSR build (reused by both layers)
    zero_i32<<<(NN + 255) / 256, 256, 0, stream>>>(counts, NN);
    hist_kernel<<<(NE + 255) / 256, 256, 0, stream>>>(eidx, counts);
    scan_phaseA<<<NT, 256, 0, stream>>>(counts, bsum);
    scan_phaseB<<<1, 128, 0, stream>>>(bsum, boff, row_ptr);
    scan_phaseC<<<NT, 256, 0, stream>>>(counts, boff, row_ptr, cursor);
    fill_kernel<<<(NE + 255) / 256, 256, 0, stream>>>(eidx, cursor, ecsr);

    const int GB = (NN + 31) / 32;  // gemm blocks (TM=32)

    // Layer 1: mean1 = agg(x); h1 = relu(mean1@W1l + x@W1r + b1); h = relu(h1@Wlin1 + blin1)
    aggregate_kernel<64><<<(NN + 15) / 16, 256, 0, stream>>>(x, row_ptr, ecsr, bufA);
    gemm_fused<64, 128, true, true><<<GB, 256, 0, stream>>>(bufA, W1l, x, W1r, b1, bufB);
    gemm_fused<128, 128, false, true><<<GB, 256, 0, stream>>>(bufB, Wlin1, nullptr, nullptr, blin1, bufC);

    // Layer 2: mean2 = agg(h); h2 = relu(mean2@W2l + h@W2r + b2); out = h2@Wlin2 + blin2
    aggregate_kernel<128><<<(NN + 7) / 8, 256, 0, stream>>>(bufC, row_ptr, ecsr, bufA);
    gemm_fused<128, 128, true, true><<<GB, 256, 0, stream>>>(bufA, W2l, bufC, W2r, b2, bufB);
    gemm_fused<128, 64, false, false><<<GB, 256, 0, stream>>>(bufB, Wlin2, nullptr, nullptr, blin2, out);
}

// Round 4
// 797.974 us; speedup vs baseline: 1.7060x; 1.7060x over previous
//
#include <hip/hip_runtime.h>
#include <cstddef>

static constexpr int NN = 100000;   // nodes
static constexpr int NE = 1600000;  // edges
static constexpr int D  = 64;
static constexpr int H  = 128;
static constexpr int O  = 64;
static constexpr int TILE = 1024;
static constexpr int NT = (NN + TILE - 1) / TILE;   // 98 scan tiles

// ---------------- CSR construction ----------------

__global__ void zero_i32(int* p, int n) {
    int i = blockIdx.x * blockDim.x + threadIdx.x;
    if (i < n) p[i] = 0;
}

// edge_index layout: src = eidx[0..NE), dst = eidx[NE..2NE)  (int32 per harness)
__global__ void hist_kernel(const int* __restrict__ eidx, int* __restrict__ counts) {
    int e = blockIdx.x * blockDim.x + threadIdx.x;
    if (e < NE) atomicAdd(&counts[eidx[NE + e]], 1);
}

__global__ void scan_phaseA(const int* __restrict__ counts, int* __restrict__ bsum) {
    __shared__ int s[256];
    int t = threadIdx.x, b = blockIdx.x;
    int base = b * TILE + t * 4;
    int acc = 0;
#pragma unroll
    for (int j = 0; j < 4; j++) { int i = base + j; if (i < NN) acc += counts[i]; }
    s[t] = acc; __syncthreads();
    for (int off = 128; off > 0; off >>= 1) {
        if (t < off) s[t] += s[t + off];
        __syncthreads();
    }
    if (t == 0) bsum[b] = s[0];
}

__global__ void scan_phaseB(const int* __restrict__ bsum, int* __restrict__ boff,
                            int* __restrict__ row_ptr) {
    __shared__ int s[128];
    int t = threadIdx.x;
    int v = (t < NT) ? bsum[t] : 0;
    s[t] = v; __syncthreads();
    for (int off = 1; off < 128; off <<= 1) {
        int x = (t >= off) ? s[t - off] : 0;
        __syncthreads();
        s[t] += x;
        __syncthreads();
    }
    boff[t] = s[t] - v;                 // exclusive
    if (t == 127) row_ptr[NN] = s[127]; // total == NE
}

__global__ void scan_phaseC(const int* __restrict__ counts, const int* __restrict__ boff,
                            int* __restrict__ row_ptr, int* __restrict__ cursor) {
    __shared__ int s[256];
    int t = threadIdx.x, b = blockIdx.x;
    int base = b * TILE + t * 4;
    int v[4];
#pragma unroll
    for (int j = 0; j < 4; j++) { int i = base + j; v[j] = (i < NN) ? counts[i] : 0; }
    int tsum = v[0] + v[1] + v[2] + v[3];
    s[t] = tsum; __syncthreads();
    for (int off = 1; off < 256; off <<= 1) {
        int x = (t >= off) ? s[t - off] : 0;
        __syncthreads();
        s[t] += x;
        __syncthreads();
    }
    int pre = boff[b] + s[t] - tsum;    // exclusive prefix for this thread's first elem
#pragma unroll
    for (int j = 0; j < 4; j++) {
        int i = base + j;
        if (i < NN) { row_ptr[i] = pre; cursor[i] = pre; }
        pre += v[j];
    }
}

__global__ void fill_kernel(const int* __restrict__ eidx, int* __restrict__ cursor,
                            int* __restrict__ ecsr) {
    int e = blockIdx.x * blockDim.x + threadIdx.x;
    if (e < NE) {
        int d = eidx[NE + e];
        int pos = atomicAdd(&cursor[d], 1);
        ecsr[pos] = eidx[e];   // store src
    }
}

// ---------------- mean aggregation (gather via CSR) ----------------
// float4 per lane: F/4 threads per node. Edge loop unrolled x4 with independent
// accumulators -> 4 outstanding 16B gathers per lane (latency -> BW bound).
template<int F>
__launch_bounds__(256)
__global__ void aggregate_kernel(const float* __restrict__ feat, const int* __restrict__ row_ptr,
                                 const int* __restrict__ ecsr, float* __restrict__ meanout) {
    constexpr int TPN = F / 4;        // threads per node
    constexpr int NPB = 256 / TPN;    // nodes per block
    int node = blockIdx.x * NPB + threadIdx.x / TPN;
    int lane = threadIdx.x % TPN;
    if (node >= NN) return;
    int beg = row_ptr[node], end = row_ptr[node + 1];
    const float4* frow = (const float4*)feat;

    float4 a0 = make_float4(0.f, 0.f, 0.f, 0.f);
    float4 a1 = a0, a2 = a0, a3 = a0;

    int i = beg;
    for (; i + 4 <= end; i += 4) {
        int s0 = ecsr[i + 0], s1 = ecsr[i + 1], s2 = ecsr[i + 2], s3 = ecsr[i + 3];
        float4 v0 = frow[(size_t)s0 * TPN + lane];
        float4 v1 = frow[(size_t)s1 * TPN + lane];
        float4 v2 = frow[(size_t)s2 * TPN + lane];
        float4 v3 = frow[(size_t)s3 * TPN + lane];
        a0.x += v0.x; a0.y += v0.y; a0.z += v0.z; a0.w += v0.w;
        a1.x += v1.x; a1.y += v1.y; a1.z += v1.z; a1.w += v1.w;
        a2.x += v2.x; a2.y += v2.y; a2.z += v2.z; a2.w += v2.w;
        a3.x += v3.x; a3.y += v3.y; a3.z += v3.z; a3.w += v3.w;
    }
    for (; i < end; i++) {
        int s0 = ecsr[i];
        float4 v0 = frow[(size_t)s0 * TPN + lane];
        a0.x += v0.x; a0.y += v0.y; a0.z += v0.z; a0.w += v0.w;
    }
    a0.x += a1.x + a2.x + a3.x;
    a0.y += a1.y + a2.y + a3.y;
    a0.z += a1.z + a2.z + a3.z;
    a0.w += a1.w + a2.w + a3.w;

    int deg = end - beg;
    float r = (deg > 0) ? 1.f / (float)deg : 0.f;
    float4 o = make_float4(a0.x * r, a0.y * r, a0.z * r, a0.w * r);
    ((float4*)meanout)[(size_t)node * TPN + lane] = o;
}

// ---------------- fused fp32 GEMM:  out = [relu]( A1@W1 [+ A2@W2] + bias ) ----------------
// A: [NN x K] row-major, W: [K x C] row-major, out: [NN x C].
// TM=32, __launch_bounds__(256,4): caps VGPR at 128 (round-3 post-mortem: without
// the bound the allocator software-pipelined the fully-unrolled k-loop to VGPR=256
// + ~1.9GB scratch spills/dispatch). #pragma unroll 2 bounds the prefetch window.
template<int K, int C, bool DUAL, bool RELU>
__launch_bounds__(256, 4)
__global__ void gemm_fused(const float* __restrict__ A1, const float* __restrict__ W1,
                           const float* __restrict__ A2, const float* __restrict__ W2,
                           const float* __restrict__ bias, float* __restrict__ out) {
    constexpr int TM  = 32;
    constexpr int KP  = K + 4;          // padded LDS row stride (keeps 16B align)
    constexpr int CG  = C / 4;          // col groups (float4 per thread)
    constexpr int RG  = 256 / CG;       // row-thread groups
    constexpr int RPT = TM / RG;        // rows per thread
    __shared__ float As1[TM * KP];
    __shared__ float As2[DUAL ? TM * KP : 4];

    const int tid  = threadIdx.x;
    const int row0 = blockIdx.x * TM;

    constexpr int NV = TM * K / 4;      // float4 count of one A tile
    for (int v = tid; v < NV; v += 256) {
        int e = v * 4; int r = e / K; int k = e % K;
        int gr = row0 + r;
        float4 a = (gr < NN) ? *(const float4*)&A1[(size_t)gr * K + k]
                             : make_float4(0.f, 0.f, 0.f, 0.f);
        *(float4*)&As1[r * KP + k] = a;
        if constexpr (DUAL) {
            float4 a2 = (gr < NN) ? *(const float4*)&A2[(size_t)gr * K + k]
                                  : make_float4(0.f, 0.f, 0.f, 0.f);
            *(float4*)&As2[r * KP + k] = a2;
        }
    }
    __syncthreads();

    const int tx = tid % CG, ty = tid / CG;
    const int c0 = tx * 4;
    const int rbase = ty * RPT;

    float acc[RPT][4];
    {
        float4 b4 = *(const float4*)&bias[c0];
#pragma unroll
        for (int i = 0; i < RPT; i++) {
            acc[i][0] = b4.x; acc[i][1] = b4.y; acc[i][2] = b4.z; acc[i][3] = b4.w;
        }
    }

#pragma unroll 2
    for (int k = 0; k < K; k += 4) {
        float w1[4][4];
#pragma unroll
        for (int kk = 0; kk < 4; kk++) {
            float4 t = *(const float4*)&W1[(size_t)(k + kk) * C + c0];
            w1[kk][0] = t.x; w1[kk][1] = t.y; w1[kk][2] = t.z; w1[kk][3] = t.w;
        }
#pragma unroll
        for (int i = 0; i < RPT; i++) {
            float4 a = *(const float4*)&As1[(rbase + i) * KP + k];
#pragma unroll
            for (int j = 0; j < 4; j++)
                acc[i][j] += a.x * w1[0][j] + a.y * w1[1][j] + a.z * w1[2][j] + a.w * w1[3][j];
        }
        if constexpr (DUAL) {
            float w2[4][4];
#pragma unroll
            for (int kk = 0; kk < 4; kk++) {
                float4 t = *(const float4*)&W2[(size_t)(k + kk) * C + c0];
                w2[kk][0] = t.x; w2[kk][1] = t.y; w2[kk][2] = t.z; w2[kk][3] = t.w;
            }
#pragma unroll
            for (int i = 0; i < RPT; i++) {
                float4 a = *(const float4*)&As2[(rbase + i) * KP + k];
#pragma unroll
                for (int j = 0; j < 4; j++)
                    acc[i][j] += a.x * w2[0][j] + a.y * w2[1][j] + a.z * w2[2][j] + a.w * w2[3][j];
            }
        }
    }

#pragma unroll
    for (int i = 0; i < RPT; i++) {
        int gr = row0 + rbase + i;
        if (gr < NN) {
            float4 o;
            o.x = RELU ? fmaxf(acc[i][0], 0.f) : acc[i][0];
            o.y = RELU ? fmaxf(acc[i][1], 0.f) : acc[i][1];
            o.z = RELU ? fmaxf(acc[i][2], 0.f) : acc[i][2];
            o.w = RELU ? fmaxf(acc[i][3], 0.f) : acc[i][3];
            *(float4*)&out[(size_t)gr * C + c0] = o;
        }
    }
}

// ---------------- launch ----------------

extern "C" void kernel_launch(void* const* d_in, const int* in_sizes, int n_in,
                              void* d_out, int out_size, void* d_ws, size_t ws_size,
                              hipStream_t stream) {
    const float* x     = (const float*)d_in[0];
    const int*   eidx  = (const int*)d_in[1];
    const float* W1l   = (const float*)d_in[2];
    const float* b1    = (const float*)d_in[3];
    const float* W1r   = (const float*)d_in[4];
    const float* Wlin1 = (const float*)d_in[5];
    const float* blin1 = (const float*)d_in[6];
    const float* W2l   = (const float*)d_in[7];
    const float* b2    = (const float*)d_in[8];
    const float* W2r   = (const float*)d_in[9];
    const float* Wlin2 = (const float*)d_in[10];
    const float* blin2 = (const float*)d_in[11];
    float* out = (float*)d_out;
    (void)in_sizes; (void)n_in; (void)out_size; (void)ws_size;

    char* ws = (char*)d_ws;
    size_t off = 0;
    auto alloc = [&](size_t bytes) -> void* {
        void* p = ws + off;
        off = (off + bytes + 255) & ~(size_t)255;
        return p;
    };
    int*   counts  = (int*)alloc((size_t)NN * 4);
    int*   bsum    = (int*)alloc(128 * 4);
    int*   boff    = (int*)alloc(128 * 4);
    int*   row_ptr = (int*)alloc((size_t)(NN + 1) * 4);
    int*   cursor  = (int*)alloc((size_t)NN * 4);
    int*   ecsr    = (int*)alloc((size_t)NE * 4);
    float* bufA    = (float*)alloc((size_t)NN * H * 4);
    float* bufB    = (float*)alloc((size_t)NN * H * 4);
    float* bufC    = (float*)alloc((size_t)NN * H * 4);

    // CSR build (reused by both layers)
    zero_i32<<<(NN + 255) / 256, 256, 0, stream>>>(counts, NN);
    hist_kernel<<<(NE + 255) / 256, 256, 0, stream>>>(eidx, counts);
    scan_phaseA<<<NT, 256, 0, stream>>>(counts, bsum);
    scan_phaseB<<<1, 128, 0, stream>>>(bsum, boff, row_ptr);
    scan_phaseC<<<NT, 256, 0, stream>>>(counts, boff, row_ptr, cursor);
    fill_kernel<<<(NE + 255) / 256, 256, 0, stream>>>(eidx, cursor, ecsr);

    const int GB = (NN + 31) / 32;  // gemm blocks (TM=32)

    // Layer 1: mean1 = agg(x); h1 = relu(mean1@W1l + x@W1r + b1); h = relu(h1@Wlin1 + blin1)
    aggregate_kernel<64><<<(NN + 15) / 16, 256, 0, stream>>>(x, row_ptr, ecsr, bufA);
    gemm_fused<64, 128, true, true><<<GB, 256, 0, stream>>>(bufA, W1l, x, W1r, b1, bufB);
    gemm_fused<128, 128, false, true><<<GB, 256, 0, stream>>>(bufB, Wlin1, nullptr, nullptr, blin1, bufC);

    // Layer 2: mean2 = agg(h); h2 = relu(mean2@W2l + h@W2r + b2); out = h2@Wlin2 + blin2
    aggregate_kernel<128><<<(NN + 7) / 8, 256, 0, stream>>>(bufC, row_ptr, ecsr, bufA);
    gemm_fused<128, 128, true, true><<<GB, 256, 0, stream>>>(bufA, W2l, bufC, W2r, b2, bufB);
    gemm_fused<128, 64, false, false><<<GB, 256, 0, stream>>>(bufB, Wlin2, nullptr, nullptr, blin2, out);
}

// Round 5
// 630.599 us; speedup vs baseline: 2.1589x; 1.2654x over previous
//
#include <hip/hip_runtime.h>
#include <cstddef>

static constexpr int NN = 100000;   // nodes
static constexpr int NE = 1600000;  // edges
static constexpr int TILE = 1024;
static constexpr int NT = (NN + TILE - 1) / TILE;   // 98 scan tiles

typedef short bf16x8 __attribute__((ext_vector_type(8)));
typedef float f32x4  __attribute__((ext_vector_type(4)));

__device__ __forceinline__ unsigned short f2bf(float f) {
    union { float f; unsigned u; } v; v.f = f;
    unsigned u = v.u + (0x7fffu + ((v.u >> 16) & 1u));   // RNE
    return (unsigned short)(u >> 16);
}
__device__ __forceinline__ float bf2f(unsigned short h) {
    union { unsigned u; float f; } v; v.u = ((unsigned)h) << 16;
    return v.f;
}

// ---------------- CSR construction ----------------

__global__ void zero_i32(int* p, int n) {
    int i = blockIdx.x * blockDim.x + threadIdx.x;
    if (i < n) p[i] = 0;
}

__global__ void hist_kernel(const int* __restrict__ eidx, int* __restrict__ counts) {
    int e = blockIdx.x * blockDim.x + threadIdx.x;
    if (e < NE) atomicAdd(&counts[eidx[NE + e]], 1);
}

__global__ void scan_phaseA(const int* __restrict__ counts, int* __restrict__ bsum) {
    __shared__ int s[256];
    int t = threadIdx.x, b = blockIdx.x;
    int base = b * TILE + t * 4;
    int acc = 0;
#pragma unroll
    for (int j = 0; j < 4; j++) { int i = base + j; if (i < NN) acc += counts[i]; }
    s[t] = acc; __syncthreads();
    for (int off = 128; off > 0; off >>= 1) {
        if (t < off) s[t] += s[t + off];
        __syncthreads();
    }
    if (t == 0) bsum[b] = s[0];
}

__global__ void scan_phaseB(const int* __restrict__ bsum, int* __restrict__ boff,
                            int* __restrict__ row_ptr) {
    __shared__ int s[128];
    int t = threadIdx.x;
    int v = (t < NT) ? bsum[t] : 0;
    s[t] = v; __syncthreads();
    for (int off = 1; off < 128; off <<= 1) {
        int x = (t >= off) ? s[t - off] : 0;
        __syncthreads();
        s[t] += x;
        __syncthreads();
    }
    boff[t] = s[t] - v;
    if (t == 127) row_ptr[NN] = s[127];
}

__global__ void scan_phaseC(const int* __restrict__ counts, const int* __restrict__ boff,
                            int* __restrict__ row_ptr, int* __restrict__ cursor) {
    __shared__ int s[256];
    int t = threadIdx.x, b = blockIdx.x;
    int base = b * TILE + t * 4;
    int v[4];
#pragma unroll
    for (int j = 0; j < 4; j++) { int i = base + j; v[j] = (i < NN) ? counts[i] : 0; }
    int tsum = v[0] + v[1] + v[2] + v[3];
    s[t] = tsum; __syncthreads();
    for (int off = 1; off < 256; off <<= 1) {
        int x = (t >= off) ? s[t - off] : 0;
        __syncthreads();
        s[t] += x;
        __syncthreads();
    }
    int pre = boff[b] + s[t] - tsum;
#pragma unroll
    for (int j = 0; j < 4; j++) {
        int i = base + j;
        if (i < NN) { row_ptr[i] = pre; cursor[i] = pre; }
        pre += v[j];
    }
}

__global__ void fill_kernel(const int* __restrict__ eidx, int* __restrict__ cursor,
                            int* __restrict__ ecsr) {
    int e = blockIdx.x * blockDim.x + threadIdx.x;
    if (e < NE) {
        int d = eidx[NE + e];
        int pos = atomicAdd(&cursor[d], 1);
        ecsr[pos] = eidx[e];
    }
}

// ---------------- conversions ----------------

// W [K x C] fp32 -> Wt'' transposed bf16 with hi/lo/hi segment layout:
// Wt[c*wld + kbase + k] = hi, + K + k = lo, + 2K + k = hi.
__global__ void convW(const float* __restrict__ W, unsigned short* __restrict__ Wt,
                      int K, int C, int wld, int kbase) {
    int t = blockIdx.x * blockDim.x + threadIdx.x;
    if (t >= K * C) return;
    int k = t / C, c = t % C;
    float v = W[t];
    unsigned short hi = f2bf(v);
    unsigned short lo = f2bf(v - bf2f(hi));
    size_t base = (size_t)c * wld + kbase;
    Wt[base + k] = hi;
    Wt[base + K + k] = lo;
    Wt[base + 2 * K + k] = hi;
}

// x [NN x 64] fp32 -> bufP cols [128..192)=hi, [192..256)=lo
__global__ void convX(const float* __restrict__ x, unsigned short* __restrict__ bufP) {
    int t = blockIdx.x * blockDim.x + threadIdx.x;
    if (t >= NN * 64) return;
    int r = t >> 6, c = t & 63;
    float v = x[t];
    unsigned short hi = f2bf(v);
    unsigned short lo = f2bf(v - bf2f(hi));
    bufP[(size_t)r * 256 + 128 + c] = hi;
    bufP[(size_t)r * 256 + 192 + c] = lo;
}

// ---------------- mean aggregation ----------------

// layer 1: gather fp32 x rows (64 feat), write bf16 pair into bufP cols [0,64)=hi,[64,128)=lo
__launch_bounds__(256)
__global__ void agg_f32(const float* __restrict__ feat, const int* __restrict__ row_ptr,
                        const int* __restrict__ ecsr, unsigned short* __restrict__ outp) {
    constexpr int TPN = 16;           // 64 feat / 4 per lane
    int node = blockIdx.x * (256 / TPN) + threadIdx.x / TPN;
    int lane = threadIdx.x % TPN;
    if (node >= NN) return;
    int beg = row_ptr[node], end = row_ptr[node + 1];
    const float4* frow = (const float4*)feat;

    float4 a0 = make_float4(0.f, 0.f, 0.f, 0.f);
    float4 a1 = a0, a2 = a0, a3 = a0;
    int i = beg;
    for (; i + 4 <= end; i += 4) {
        int s0 = ecsr[i], s1 = ecsr[i + 1], s2 = ecsr[i + 2], s3 = ecsr[i + 3];
        float4 v0 = frow[(size_t)s0 * TPN + lane];
        float4 v1 = frow[(size_t)s1 * TPN + lane];
        float4 v2 = frow[(size_t)s2 * TPN + lane];
        float4 v3 = frow[(size_t)s3 * TPN + lane];
        a0.x += v0.x; a0.y += v0.y; a0.z += v0.z; a0.w += v0.w;
        a1.x += v1.x; a1.y += v1.y; a1.z += v1.z; a1.w += v1.w;
        a2.x += v2.x; a2.y += v2.y; a2.z += v2.z; a2.w += v2.w;
        a3.x += v3.x; a3.y += v3.y; a3.z += v3.z; a3.w += v3.w;
    }
    for (; i < end; i++) {
        float4 v0 = frow[(size_t)ecsr[i] * TPN + lane];
        a0.x += v0.x; a0.y += v0.y; a0.z += v0.z; a0.w += v0.w;
    }
    float m[4];
    m[0] = a0.x + a1.x + a2.x + a3.x;
    m[1] = a0.y + a1.y + a2.y + a3.y;
    m[2] = a0.z + a1.z + a2.z + a3.z;
    m[3] = a0.w + a1.w + a2.w + a3.w;
    int deg = end - beg;
    float r = (deg > 0) ? 1.f / (float)deg : 0.f;
    ushort4 hi, lo;
    unsigned short* h = (unsigned short*)&hi;
    unsigned short* l = (unsigned short*)&lo;
#pragma unroll
    for (int j = 0; j < 4; j++) {
        float v = m[j] * r;
        h[j] = f2bf(v);
        l[j] = f2bf(v - bf2f(h[j]));
    }
    unsigned short* orow = outp + (size_t)node * 256 + lane * 4;
    *(ushort4*)orow = hi;
    *(ushort4*)(orow + 64) = lo;
}

// layer 2: gather bf16-pair h rows (bufQ cols [256,384)=hi,[384,512)=lo),
// write mean pair into bufQ cols [0,128)=hi,[128,256)=lo
__launch_bounds__(256)
__global__ void agg_pair(const unsigned short* __restrict__ hbuf, const int* __restrict__ row_ptr,
                         const int* __restrict__ ecsr, unsigned short* __restrict__ outp) {
    constexpr int TPN = 32;           // 128 feat / 4 per lane
    int node = blockIdx.x * (256 / TPN) + threadIdx.x / TPN;
    int lane = threadIdx.x % TPN;
    if (node >= NN) return;
    int beg = row_ptr[node], end = row_ptr[node + 1];

    float m[4] = {0.f, 0.f, 0.f, 0.f};
    int i = beg;
    for (; i + 2 <= end; i += 2) {
        int s0 = ecsr[i], s1 = ecsr[i + 1];
        ushort4 h0 = *(const ushort4*)&hbuf[(size_t)s0 * 512 + 256 + lane * 4];
        ushort4 l0 = *(const ushort4*)&hbuf[(size_t)s0 * 512 + 384 + lane * 4];
        ushort4 h1 = *(const ushort4*)&hbuf[(size_t)s1 * 512 + 256 + lane * 4];
        ushort4 l1 = *(const ushort4*)&hbuf[(size_t)s1 * 512 + 384 + lane * 4];
        m[0] += bf2f(h0.x) + bf2f(l0.x) + bf2f(h1.x) + bf2f(l1.x);
        m[1] += bf2f(h0.y) + bf2f(l0.y) + bf2f(h1.y) + bf2f(l1.y);
        m[2] += bf2f(h0.z) + bf2f(l0.z) + bf2f(h1.z) + bf2f(l1.z);
        m[3] += bf2f(h0.w) + bf2f(l0.w) + bf2f(h1.w) + bf2f(l1.w);
    }
    for (; i < end; i++) {
        int s0 = ecsr[i];
        ushort4 h0 = *(const ushort4*)&hbuf[(size_t)s0 * 512 + 256 + lane * 4];
        ushort4 l0 = *(const ushort4*)&hbuf[(size_t)s0 * 512 + 384 + lane * 4];
        m[0] += bf2f(h0.x) + bf2f(l0.x);
        m[1] += bf2f(h0.y) + bf2f(l0.y);
        m[2] += bf2f(h0.z) + bf2f(l0.z);
        m[3] += bf2f(h0.w) + bf2f(l0.w);
    }
    int deg = end - beg;
    float r = (deg > 0) ? 1.f / (float)deg : 0.f;
    ushort4 hi, lo;
    unsigned short* h = (unsigned short*)&hi;
    unsigned short* l = (unsigned short*)&lo;
#pragma unroll
    for (int j = 0; j < 4; j++) {
        float v = m[j] * r;
        h[j] = f2bf(v);
        l[j] = f2bf(v - bf2f(h[j]));
    }
    unsigned short* orow = outp + (size_t)node * 512 + lane * 4;
    *(ushort4*)orow = hi;
    *(ushort4*)(orow + 128) = lo;
}

// ---------------- MFMA GEMM over hi/lo segmented bf16 ----------------
// out[M x C] = sum_s Aseg(s) @ Wseg(s) + bias, optional relu.
// A physical: [A1hi(K) | A1lo(K) | A2hi(K) | A2lo(K)] (dual) or [Ahi|Alo], row stride lda.
// Wt'' physical: transposed [C x S*K] with rows [hi,lo,hi] per source matrix (convW).
// 3-term split: hi*hi + hi*lo + lo*hi (lo*lo dropped, ~1e-4 abs).
// Tile: BM x C per block, 4 waves as 64x64 quadrants, 4x4 MFMA 16x16x32 tiles, BK=64.
// LDS rows padded to 72 bf16 (144B) -> conflict-free ds_read_b128.
template<int K, int C, int S, bool RELU, bool PAIR>
__launch_bounds__(256, 2)
__global__ void gemm_mfma(const unsigned short* __restrict__ A, int lda,
                          const unsigned short* __restrict__ Wt,
                          const float* __restrict__ bias,
                          unsigned short* __restrict__ outp, int old_, int obase,
                          float* __restrict__ outf) {
    constexpr int BM  = (C == 128) ? 128 : 256;
    constexpr int WLD = S * K;
    constexpr int NC  = S * K / 64;
    __shared__ unsigned short As[BM * 72];
    __shared__ unsigned short Ws[C * 72];

    const int tid  = threadIdx.x;
    const int lane = tid & 63, wave = tid >> 6;
    const int lrow = lane & 15, quad = lane >> 4;
    const int wrow0 = (C == 128) ? (wave >> 1) * 64 : wave * 64;
    const int wcol0 = (C == 128) ? (wave & 1) * 64 : 0;
    const int row0  = blockIdx.x * BM;

    f32x4 acc[4][4];
#pragma unroll
    for (int a = 0; a < 4; a++)
#pragma unroll
        for (int b = 0; b < 4; b++) acc[a][b] = (f32x4){0.f, 0.f, 0.f, 0.f};

#pragma unroll 1
    for (int cc = 0; cc < NC; ++cc) {
        int seg = (cc * 64) / K, inner = (cc * 64) % K;
        int acol = (seg / 3) * 2 * K + ((seg % 3) == 2 ? K : 0) + inner;
        // stage A chunk [BM x 64]
        for (int t = tid; t < BM * 8; t += 256) {
            int r = t >> 3, c8 = (t & 7) * 8;
            int gr = row0 + r;
            uint4 v = make_uint4(0u, 0u, 0u, 0u);
            if (gr < NN) v = *(const uint4*)&A[(size_t)gr * lda + acol + c8];
            *(uint4*)&As[r * 72 + c8] = v;
        }
        // stage Wt chunk [C x 64]
        for (int t = tid; t < C * 8; t += 256) {
            int wr = t >> 3, c8 = (t & 7) * 8;
            *(uint4*)&Ws[wr * 72 + c8] = *(const uint4*)&Wt[(size_t)wr * WLD + cc * 64 + c8];
        }
        __syncthreads();
#pragma unroll
        for (int ks = 0; ks < 2; ++ks) {
            bf16x8 af[4], bfr[4];
#pragma unroll
            for (int rt = 0; rt < 4; rt++)
                af[rt] = *(const bf16x8*)&As[(wrow0 + rt * 16 + lrow) * 72 + ks * 32 + quad * 8];
#pragma unroll
            for (int ct = 0; ct < 4; ct++)
                bfr[ct] = *(const bf16x8*)&Ws[(wcol0 + ct * 16 + lrow) * 72 + ks * 32 + quad * 8];
#pragma unroll
            for (int rt = 0; rt < 4; rt++)
#pragma unroll
                for (int ct = 0; ct < 4; ct++)
                    acc[rt][ct] = __builtin_amdgcn_mfma_f32_16x16x32_bf16(
                        af[rt], bfr[ct], acc[rt][ct], 0, 0, 0);
        }
        __syncthreads();
    }

    // epilogue: C/D layout col=lane&15, row=quad*4+reg [m89/m91 verified]
    float bcol[4];
#pragma unroll
    for (int ct = 0; ct < 4; ct++) bcol[ct] = bias[wcol0 + ct * 16 + lrow];
#pragma unroll
    for (int rt = 0; rt < 4; rt++) {
#pragma unroll
        for (int ct = 0; ct < 4; ct++) {
#pragma unroll
            for (int r = 0; r < 4; r++) {
                int grow = row0 + wrow0 + rt * 16 + quad * 4 + r;
                if (grow < NN) {
                    int col = wcol0 + ct * 16 + lrow;
                    float v = acc[rt][ct][r] + bcol[ct];
                    if (RELU) v = fmaxf(v, 0.f);
                    if (PAIR) {
                        unsigned short hi = f2bf(v);
                        unsigned short lo = f2bf(v - bf2f(hi));
                        outp[(size_t)grow * old_ + obase + col] = hi;
                        outp[(size_t)grow * old_ + obase + C + col] = lo;
                    } else {
                        outf[(size_t)grow * C + col] = v;
                    }
                }
            }
        }
    }
}

// ---------------- launch ----------------

extern "C" void kernel_launch(void* const* d_in, const int* in_sizes, int n_in,
                              void* d_out, int out_size, void* d_ws, size_t ws_size,
                              hipStream_t stream) {
    const float* x     = (const float*)d_in[0];
    const int*   eidx  = (const int*)d_in[1];
    const float* W1l   = (const float*)d_in[2];
    const float* b1    = (const float*)d_in[3];
    const float* W1r   = (const float*)d_in[4];
    const float* Wlin1 = (const float*)d_in[5];
    const float* blin1 = (const float*)d_in[6];
    const float* W2l   = (const float*)d_in[7];
    const float* b2    = (const float*)d_in[8];
    const float* W2r   = (const float*)d_in[9];
    const float* Wlin2 = (const float*)d_in[10];
    const float* blin2 = (const float*)d_in[11];
    float* out = (float*)d_out;
    (void)in_sizes; (void)n_in; (void)out_size; (void)ws_size;

    char* ws = (char*)d_ws;
    size_t off = 0;
    auto alloc = [&](size_t bytes) -> void* {
        void* p = ws + off;
        off = (off + bytes + 255) & ~(size_t)255;
        return p;
    };
    int* counts  = (int*)alloc((size_t)NN * 4);          // also reused as cursor
    int* bsum    = (int*)alloc(128 * 4);
    int* boff    = (int*)alloc(128 * 4);
    int* row_ptr = (int*)alloc((size_t)(NN + 1) * 4);
    int* ecsr    = (int*)alloc((size_t)NE * 4);
    unsigned short* Wt1  = (unsigned short*)alloc((size_t)128 * 384 * 2);
    unsigned short* Wtl1 = (unsigned short*)alloc((size_t)128 * 384 * 2);
    unsigned short* Wt2  = (unsigned short*)alloc((size_t)128 * 768 * 2);
    unsigned short* Wtf  = (unsigned short*)alloc((size_t)64  * 384 * 2);
    unsigned short* bufP = (unsigned short*)alloc((size_t)NN * 256 * 2);  // 51.2 MB
    unsigned short* bufQ = (unsigned short*)alloc((size_t)NN * 512 * 2);  // 102.4 MB
    int* cursor = counts;   // counts dead after scan_phaseC (safe: phaseC reads before writes)

    // CSR build
    zero_i32<<<(NN + 255) / 256, 256, 0, stream>>>(counts, NN);
    hist_kernel<<<(NE + 255) / 256, 256, 0, stream>>>(eidx, counts);
    scan_phaseA<<<NT, 256, 0, stream>>>(counts, bsum);
    scan_phaseB<<<1, 128, 0, stream>>>(bsum, boff, row_ptr);
    scan_phaseC<<<NT, 256, 0, stream>>>(counts, boff, row_ptr, cursor);
    fill_kernel<<<(NE + 255) / 256, 256, 0, stream>>>(eidx, cursor, ecsr);

    // weight conversions (tiny)
    convW<<<32, 256, 0, stream>>>(W1l,   Wt1,  64, 128, 384, 0);
    convW<<<32, 256, 0, stream>>>(W1r,   Wt1,  64, 128, 384, 192);
    convW<<<64, 256, 0, stream>>>(Wlin1, Wtl1, 128, 128, 384, 0);
    convW<<<64, 256, 0, stream>>>(W2l,   Wt2,  128, 128, 768, 0);
    convW<<<64, 256, 0, stream>>>(W2r,   Wt2,  128, 128, 768, 384);
    convW<<<32, 256, 0, stream>>>(Wlin2, Wtf,  128, 64, 384, 0);

    // x -> bf16 pair (bufP cols 128..255); mean1 -> bufP cols 0..127
    convX<<<(NN * 64 + 255) / 256, 256, 0, stream>>>(x, bufP);
    agg_f32<<<(NN + 15) / 16, 256, 0, stream>>>(x, row_ptr, ecsr, bufP);

    const int GB128 = (NN + 127) / 128;
    const int GB256 = (NN + 255) / 256;

    // L1 SAGE: bufP[mean|x] @ [W1l;W1r] -> h1 pair into bufQ cols 0..255
    gemm_mfma<64, 128, 6, true, true><<<GB128, 256, 0, stream>>>(
        bufP, 256, Wt1, b1, bufQ, 512, 0, nullptr);
    // lin1: bufQ cols 0..255 @ Wlin1 -> h pair into bufQ cols 256..511
    gemm_mfma<128, 128, 3, true, true><<<GB128, 256, 0, stream>>>(
        bufQ, 512, Wtl1, blin1, bufQ, 512, 256, nullptr);
    // mean2 from h pairs -> bufQ cols 0..255
    agg_pair<<<(NN + 7) / 8, 256, 0, stream>>>(bufQ, row_ptr, ecsr, bufQ);
    // L2 SAGE: bufQ[mean2|h] @ [W2l;W2r] -> h2 pair into bufP
    gemm_mfma<128, 128, 6, true, true><<<GB128, 256, 0, stream>>>(
        bufQ, 512, Wt2, b2, bufP, 256, 0, nullptr);
    // final: bufP @ Wlin2 + blin2 -> fp32 out (no relu)
    gemm_mfma<128, 64, 3, false, false><<<GB256, 256, 0, stream>>>(
        bufP, 256, Wtf, blin2, nullptr, 0, 0, out);
}

// Round 6
// 505.228 us; speedup vs baseline: 2.6946x; 1.2481x over previous
//
#include <hip/hip_runtime.h>
#include <cstddef>

static constexpr int NN = 100000;   // nodes
static constexpr int NE = 1600000;  // edges
static constexpr int NODE_SHIFT = 8;                       // 256 nodes per bucket
static constexpr int NB = (NN + 255) >> NODE_SHIFT;        // 391 buckets
static constexpr int CHUNK = 8192;                         // edges per binning block
static constexpr int NCH = (NE + CHUNK - 1) / CHUNK;       // 196 chunks

typedef short bf16x8 __attribute__((ext_vector_type(8)));
typedef float f32x4  __attribute__((ext_vector_type(4)));

__device__ __forceinline__ unsigned short f2bf(float f) {
    union { float f; unsigned u; } v; v.f = f;
    unsigned u = v.u + (0x7fffu + ((v.u >> 16) & 1u));   // RNE
    return (unsigned short)(u >> 16);
}
__device__ __forceinline__ float bf2f(unsigned short h) {
    union { unsigned u; float f; } v; v.u = ((unsigned)h) << 16;
    return v.f;
}

// ---------------- bucketed CSR construction ----------------
// Round-5 post-mortem: atomic fill_kernel had 16x write amplification
// (WRITE_SIZE 105MB for 6.4MB of ecsr; random 4B scatters from all XCDs).
// Bucketed build keeps each written region owned by one block -> L2 combines.

__global__ void zero_i32(int* p, int n) {
    int i = blockIdx.x * blockDim.x + threadIdx.x;
    if (i < n) p[i] = 0;
}

__global__ void bucket_count(const int* __restrict__ eidx, int* __restrict__ bcnt) {
    __shared__ int h[NB];
    for (int i = threadIdx.x; i < NB; i += 256) h[i] = 0;
    __syncthreads();
    int base = blockIdx.x * CHUNK;
    int end = min(base + CHUNK, NE);
    for (int e = base + threadIdx.x; e < end; e += 256)
        atomicAdd(&h[eidx[NE + e] >> NODE_SHIFT], 1);
    __syncthreads();
    for (int i = threadIdx.x; i < NB; i += 256)
        if (h[i]) atomicAdd(&bcnt[i], h[i]);
}

// single block: exclusive scan of bucket counts -> bbase (and cursor copy)
__global__ void bucket_scan(const int* __restrict__ bcnt, int* __restrict__ bbase,
                            int* __restrict__ bcur, int* __restrict__ row_ptr) {
    __shared__ int s[512];
    int t = threadIdx.x;
    int v = (t < NB) ? bcnt[t] : 0;
    s[t] = v; __syncthreads();
    for (int off = 1; off < 512; off <<= 1) {
        int x = (t >= off) ? s[t - off] : 0;
        __syncthreads();
        s[t] += x;
        __syncthreads();
    }
    if (t < NB) { int e = s[t] - v; bbase[t] = e; bcur[t] = e; }
    if (t == 0) { bbase[NB] = NE; row_ptr[NN] = NE; }
}

// scatter (src,dst) pairs into bucket-major order; contiguous runs per (block,bucket)
__global__ void bucket_scatter(const int* __restrict__ eidx, int* __restrict__ bcur,
                               uint2* __restrict__ pairs) {
    __shared__ int h[NB];
    __shared__ int cur[NB];
    __shared__ int off[NB];
    for (int i = threadIdx.x; i < NB; i += 256) { h[i] = 0; cur[i] = 0; }
    __syncthreads();
    int base = blockIdx.x * CHUNK;
    int end = min(base + CHUNK, NE);
    for (int e = base + threadIdx.x; e < end; e += 256)
        atomicAdd(&h[eidx[NE + e] >> NODE_SHIFT], 1);
    __syncthreads();
    for (int i = threadIdx.x; i < NB; i += 256)
        off[i] = h[i] ? atomicAdd(&bcur[i], h[i]) : 0;
    __syncthreads();
    for (int e = base + threadIdx.x; e < end; e += 256) {
        int d = eidx[NE + e], s = eidx[e];
        int b = d >> NODE_SHIFT;
        int p = atomicAdd(&cur[b], 1);
        pairs[off[b] + p] = make_uint2((unsigned)s, (unsigned)d);
    }
}

// one block per bucket: per-node LDS histogram + scan -> row_ptr, scatter src -> ecsr
__launch_bounds__(256)
__global__ void bucket_csr(const uint2* __restrict__ pairs, const int* __restrict__ bbase,
                           int* __restrict__ row_ptr, int* __restrict__ ecsr) {
    __shared__ int hist[256];
    __shared__ int scn[256];
    __shared__ int cur[256];
    int b = blockIdx.x, t = threadIdx.x;
    int ebeg = bbase[b], eend = bbase[b + 1];
    int node0 = b << NODE_SHIFT;
    hist[t] = 0;
    __syncthreads();
    for (int e = ebeg + t; e < eend; e += 256)
        atomicAdd(&hist[pairs[e].y & 255u], 1);
    __syncthreads();
    int v = hist[t];
    scn[t] = v; __syncthreads();
    for (int off = 1; off < 256; off <<= 1) {
        int x = (t >= off) ? scn[t - off] : 0;
        __syncthreads();
        scn[t] += x;
        __syncthreads();
    }
    int excl = scn[t] - v;
    int node = node0 + t;
    if (node < NN) row_ptr[node] = ebeg + excl;
    cur[t] = excl;
    __syncthreads();
    for (int e = ebeg + t; e < eend; e += 256) {
        uint2 pr = pairs[e];
        int p = atomicAdd(&cur[pr.y & 255u], 1);
        ecsr[ebeg + p] = (int)pr.x;
    }
}

// ---------------- conversions ----------------

// W [K x C] fp32 -> Wt'' transposed bf16 with hi/lo/hi segment layout:
// Wt[c*wld + kbase + k] = hi, + K + k = lo, + 2K + k = hi.
__global__ void convW(const float* __restrict__ W, unsigned short* __restrict__ Wt,
                      int K, int C, int wld, int kbase) {
    int t = blockIdx.x * blockDim.x + threadIdx.x;
    if (t >= K * C) return;
    int k = t / C, c = t % C;
    float v = W[t];
    unsigned short hi = f2bf(v);
    unsigned short lo = f2bf(v - bf2f(hi));
    size_t base = (size_t)c * wld + kbase;
    Wt[base + k] = hi;
    Wt[base + K + k] = lo;
    Wt[base + 2 * K + k] = hi;
}

// x [NN x 64] fp32 -> bufP cols [128..192)=hi, [192..256)=lo
__global__ void convX(const float* __restrict__ x, unsigned short* __restrict__ bufP) {
    int t = blockIdx.x * blockDim.x + threadIdx.x;
    if (t >= NN * 64) return;
    int r = t >> 6, c = t & 63;
    float v = x[t];
    unsigned short hi = f2bf(v);
    unsigned short lo = f2bf(v - bf2f(hi));
    bufP[(size_t)r * 256 + 128 + c] = hi;
    bufP[(size_t)r * 256 + 192 + c] = lo;
}

// ---------------- mean aggregation ----------------

// layer 1: gather fp32 x rows (64 feat), write bf16 pair into bufP cols [0,64)=hi,[64,128)=lo
__launch_bounds__(256)
__global__ void agg_f32(const float* __restrict__ feat, const int* __restrict__ row_ptr,
                        const int* __restrict__ ecsr, unsigned short* __restrict__ outp) {
    constexpr int TPN = 16;           // 64 feat / 4 per lane
    int node = blockIdx.x * (256 / TPN) + threadIdx.x / TPN;
    int lane = threadIdx.x % TPN;
    if (node >= NN) return;
    int beg = row_ptr[node], end = row_ptr[node + 1];
    const float4* frow = (const float4*)feat;

    float4 a0 = make_float4(0.f, 0.f, 0.f, 0.f);
    float4 a1 = a0, a2 = a0, a3 = a0;
    int i = beg;
    for (; i + 4 <= end; i += 4) {
        int s0 = ecsr[i], s1 = ecsr[i + 1], s2 = ecsr[i + 2], s3 = ecsr[i + 3];
        float4 v0 = frow[(size_t)s0 * TPN + lane];
        float4 v1 = frow[(size_t)s1 * TPN + lane];
        float4 v2 = frow[(size_t)s2 * TPN + lane];
        float4 v3 = frow[(size_t)s3 * TPN + lane];
        a0.x += v0.x; a0.y += v0.y; a0.z += v0.z; a0.w += v0.w;
        a1.x += v1.x; a1.y += v1.y; a1.z += v1.z; a1.w += v1.w;
        a2.x += v2.x; a2.y += v2.y; a2.z += v2.z; a2.w += v2.w;
        a3.x += v3.x; a3.y += v3.y; a3.z += v3.z; a3.w += v3.w;
    }
    for (; i < end; i++) {
        float4 v0 = frow[(size_t)ecsr[i] * TPN + lane];
        a0.x += v0.x; a0.y += v0.y; a0.z += v0.z; a0.w += v0.w;
    }
    float m[4];
    m[0] = a0.x + a1.x + a2.x + a3.x;
    m[1] = a0.y + a1.y + a2.y + a3.y;
    m[2] = a0.z + a1.z + a2.z + a3.z;
    m[3] = a0.w + a1.w + a2.w + a3.w;
    int deg = end - beg;
    float r = (deg > 0) ? 1.f / (float)deg : 0.f;
    ushort4 hi, lo;
    unsigned short* h = (unsigned short*)&hi;
    unsigned short* l = (unsigned short*)&lo;
#pragma unroll
    for (int j = 0; j < 4; j++) {
        float v = m[j] * r;
        h[j] = f2bf(v);
        l[j] = f2bf(v - bf2f(h[j]));
    }
    unsigned short* orow = outp + (size_t)node * 256 + lane * 4;
    *(ushort4*)orow = hi;
    *(ushort4*)(orow + 64) = lo;
}

// layer 2: gather bf16-pair h rows (bufQ cols [256,384)=hi,[384,512)=lo),
// write mean pair into bufQ cols [0,128)=hi,[128,256)=lo
__launch_bounds__(256)
__global__ void agg_pair(const unsigned short* __restrict__ hbuf, const int* __restrict__ row_ptr,
                         const int* __restrict__ ecsr, unsigned short* __restrict__ outp) {
    constexpr int TPN = 32;           // 128 feat / 4 per lane
    int node = blockIdx.x * (256 / TPN) + threadIdx.x / TPN;
    int lane = threadIdx.x % TPN;
    if (node >= NN) return;
    int beg = row_ptr[node], end = row_ptr[node + 1];

    float m[4] = {0.f, 0.f, 0.f, 0.f};
    int i = beg;
    for (; i + 2 <= end; i += 2) {
        int s0 = ecsr[i], s1 = ecsr[i + 1];
        ushort4 h0 = *(const ushort4*)&hbuf[(size_t)s0 * 512 + 256 + lane * 4];
        ushort4 l0 = *(const ushort4*)&hbuf[(size_t)s0 * 512 + 384 + lane * 4];
        ushort4 h1 = *(const ushort4*)&hbuf[(size_t)s1 * 512 + 256 + lane * 4];
        ushort4 l1 = *(const ushort4*)&hbuf[(size_t)s1 * 512 + 384 + lane * 4];
        m[0] += bf2f(h0.x) + bf2f(l0.x) + bf2f(h1.x) + bf2f(l1.x);
        m[1] += bf2f(h0.y) + bf2f(l0.y) + bf2f(h1.y) + bf2f(l1.y);
        m[2] += bf2f(h0.z) + bf2f(l0.z) + bf2f(h1.z) + bf2f(l1.z);
        m[3] += bf2f(h0.w) + bf2f(l0.w) + bf2f(h1.w) + bf2f(l1.w);
    }
    for (; i < end; i++) {
        int s0 = ecsr[i];
        ushort4 h0 = *(const ushort4*)&hbuf[(size_t)s0 * 512 + 256 + lane * 4];
        ushort4 l0 = *(const ushort4*)&hbuf[(size_t)s0 * 512 + 384 + lane * 4];
        m[0] += bf2f(h0.x) + bf2f(l0.x);
        m[1] += bf2f(h0.y) + bf2f(l0.y);
        m[2] += bf2f(h0.z) + bf2f(l0.z);
        m[3] += bf2f(h0.w) + bf2f(l0.w);
    }
    int deg = end - beg;
    float r = (deg > 0) ? 1.f / (float)deg : 0.f;
    ushort4 hi, lo;
    unsigned short* h = (unsigned short*)&hi;
    unsigned short* l = (unsigned short*)&lo;
#pragma unroll
    for (int j = 0; j < 4; j++) {
        float v = m[j] * r;
        h[j] = f2bf(v);
        l[j] = f2bf(v - bf2f(h[j]));
    }
    unsigned short* orow = outp + (size_t)node * 512 + lane * 4;
    *(ushort4*)orow = hi;
    *(ushort4*)(orow + 128) = lo;
}

// ---------------- MFMA GEMM over hi/lo segmented bf16 ----------------
template<int K, int C, int S, bool RELU, bool PAIR>
__launch_bounds__(256, 2)
__global__ void gemm_mfma(const unsigned short* __restrict__ A, int lda,
                          const unsigned short* __restrict__ Wt,
                          const float* __restrict__ bias,
                          unsigned short* __restrict__ outp, int old_, int obase,
                          float* __restrict__ outf) {
    constexpr int BM  = (C == 128) ? 128 : 256;
    constexpr int WLD = S * K;
    constexpr int NC  = S * K / 64;
    __shared__ unsigned short As[BM * 72];
    __shared__ unsigned short Ws[C * 72];

    const int tid  = threadIdx.x;
    const int lane = tid & 63, wave = tid >> 6;
    const int lrow = lane & 15, quad = lane >> 4;
    const int wrow0 = (C == 128) ? (wave >> 1) * 64 : wave * 64;
    const int wcol0 = (C == 128) ? (wave & 1) * 64 : 0;
    const int row0  = blockIdx.x * BM;

    f32x4 acc[4][4];
#pragma unroll
    for (int a = 0; a < 4; a++)
#pragma unroll
        for (int b = 0; b < 4; b++) acc[a][b] = (f32x4){0.f, 0.f, 0.f, 0.f};

#pragma unroll 1
    for (int cc = 0; cc < NC; ++cc) {
        int seg = (cc * 64) / K, inner = (cc * 64) % K;
        int acol = (seg / 3) * 2 * K + ((seg % 3) == 2 ? K : 0) + inner;
        for (int t = tid; t < BM * 8; t += 256) {
            int r = t >> 3, c8 = (t & 7) * 8;
            int gr = row0 + r;
            uint4 v = make_uint4(0u, 0u, 0u, 0u);
            if (gr < NN) v = *(const uint4*)&A[(size_t)gr * lda + acol + c8];
            *(uint4*)&As[r * 72 + c8] = v;
        }
        for (int t = tid; t < C * 8; t += 256) {
            int wr = t >> 3, c8 = (t & 7) * 8;
            *(uint4*)&Ws[wr * 72 + c8] = *(const uint4*)&Wt[(size_t)wr * WLD + cc * 64 + c8];
        }
        __syncthreads();
#pragma unroll
        for (int ks = 0; ks < 2; ++ks) {
            bf16x8 af[4], bfr[4];
#pragma unroll
            for (int rt = 0; rt < 4; rt++)
                af[rt] = *(const bf16x8*)&As[(wrow0 + rt * 16 + lrow) * 72 + ks * 32 + quad * 8];
#pragma unroll
            for (int ct = 0; ct < 4; ct++)
                bfr[ct] = *(const bf16x8*)&Ws[(wcol0 + ct * 16 + lrow) * 72 + ks * 32 + quad * 8];
#pragma unroll
            for (int rt = 0; rt < 4; rt++)
#pragma unroll
                for (int ct = 0; ct < 4; ct++)
                    acc[rt][ct] = __builtin_amdgcn_mfma_f32_16x16x32_bf16(
                        af[rt], bfr[ct], acc[rt][ct], 0, 0, 0);
        }
        __syncthreads();
    }

    float bcol[4];
#pragma unroll
    for (int ct = 0; ct < 4; ct++) bcol[ct] = bias[wcol0 + ct * 16 + lrow];
#pragma unroll
    for (int rt = 0; rt < 4; rt++) {
#pragma unroll
        for (int ct = 0; ct < 4; ct++) {
#pragma unroll
            for (int r = 0; r < 4; r++) {
                int grow = row0 + wrow0 + rt * 16 + quad * 4 + r;
                if (grow < NN) {
                    int col = wcol0 + ct * 16 + lrow;
                    float v = acc[rt][ct][r] + bcol[ct];
                    if (RELU) v = fmaxf(v, 0.f);
                    if (PAIR) {
                        unsigned short hi = f2bf(v);
                        unsigned short lo = f2bf(v - bf2f(hi));
                        outp[(size_t)grow * old_ + obase + col] = hi;
                        outp[(size_t)grow * old_ + obase + C + col] = lo;
                    } else {
                        outf[(size_t)grow * C + col] = v;
                    }
                }
            }
        }
    }
}

// ---------------- launch ----------------

extern "C" void kernel_launch(void* const* d_in, const int* in_sizes, int n_in,
                              void* d_out, int out_size, void* d_ws, size_t ws_size,
                              hipStream_t stream) {
    const float* x     = (const float*)d_in[0];
    const int*   eidx  = (const int*)d_in[1];
    const float* W1l   = (const float*)d_in[2];
    const float* b1    = (const float*)d_in[3];
    const float* W1r   = (const float*)d_in[4];
    const float* Wlin1 = (const float*)d_in[5];
    const float* blin1 = (const float*)d_in[6];
    const float* W2l   = (const float*)d_in[7];
    const float* b2    = (const float*)d_in[8];
    const float* W2r   = (const float*)d_in[9];
    const float* Wlin2 = (const float*)d_in[10];
    const float* blin2 = (const float*)d_in[11];
    float* out = (float*)d_out;
    (void)in_sizes; (void)n_in; (void)out_size; (void)ws_size;

    char* ws = (char*)d_ws;
    size_t off = 0;
    auto alloc = [&](size_t bytes) -> void* {
        void* p = ws + off;
        off = (off + bytes + 255) & ~(size_t)255;
        return p;
    };
    int* bcnt    = (int*)alloc((size_t)NB * 4);
    int* bbase   = (int*)alloc((size_t)(NB + 1) * 4);
    int* bcur    = (int*)alloc((size_t)NB * 4);
    int* row_ptr = (int*)alloc((size_t)(NN + 1) * 4);
    int* ecsr    = (int*)alloc((size_t)NE * 4);
    uint2* pairs = (uint2*)alloc((size_t)NE * 8);
    unsigned short* Wt1  = (unsigned short*)alloc((size_t)128 * 384 * 2);
    unsigned short* Wtl1 = (unsigned short*)alloc((size_t)128 * 384 * 2);
    unsigned short* Wt2  = (unsigned short*)alloc((size_t)128 * 768 * 2);
    unsigned short* Wtf  = (unsigned short*)alloc((size_t)64  * 384 * 2);
    unsigned short* bufP = (unsigned short*)alloc((size_t)NN * 256 * 2);  // 51.2 MB
    unsigned short* bufQ = (unsigned short*)alloc((size_t)NN * 512 * 2);  // 102.4 MB

    // bucketed CSR build
    zero_i32<<<(NB + 255) / 256, 256, 0, stream>>>(bcnt, NB);
    bucket_count<<<NCH, 256, 0, stream>>>(eidx, bcnt);
    bucket_scan<<<1, 512, 0, stream>>>(bcnt, bbase, bcur, row_ptr);
    bucket_scatter<<<NCH, 256, 0, stream>>>(eidx, bcur, pairs);
    bucket_csr<<<NB, 256, 0, stream>>>(pairs, bbase, row_ptr, ecsr);

    // weight conversions (tiny)
    convW<<<32, 256, 0, stream>>>(W1l,   Wt1,  64, 128, 384, 0);
    convW<<<32, 256, 0, stream>>>(W1r,   Wt1,  64, 128, 384, 192);
    convW<<<64, 256, 0, stream>>>(Wlin1, Wtl1, 128, 128, 384, 0);
    convW<<<64, 256, 0, stream>>>(W2l,   Wt2,  128, 128, 768, 0);
    convW<<<64, 256, 0, stream>>>(W2r,   Wt2,  128, 128, 768, 384);
    convW<<<32, 256, 0, stream>>>(Wlin2, Wtf,  128, 64, 384, 0);

    // x -> bf16 pair (bufP cols 128..255); mean1 -> bufP cols 0..127
    convX<<<(NN * 64 + 255) / 256, 256, 0, stream>>>(x, bufP);
    agg_f32<<<(NN + 15) / 16, 256, 0, stream>>>(x, row_ptr, ecsr, bufP);

    const int GB128 = (NN + 127) / 128;
    const int GB256 = (NN + 255) / 256;

    // L1 SAGE: bufP[mean|x] @ [W1l;W1r] -> h1 pair into bufQ cols 0..255
    gemm_mfma<64, 128, 6, true, true><<<GB128, 256, 0, stream>>>(
        bufP, 256, Wt1, b1, bufQ, 512, 0, nullptr);
    // lin1: bufQ cols 0..255 @ Wlin1 -> h pair into bufQ cols 256..511
    gemm_mfma<128, 128, 3, true, true><<<GB128, 256, 0, stream>>>(
        bufQ, 512, Wtl1, blin1, bufQ, 512, 256, nullptr);
    // mean2 from h pairs -> bufQ cols 0..255
    agg_pair<<<(NN + 7) / 8, 256, 0, stream>>>(bufQ, row_ptr, ecsr, bufQ);
    // L2 SAGE: bufQ[mean2|h] @ [W2l;W2r] -> h2 pair into bufP
    gemm_mfma<128, 128, 6, true, true><<<GB128, 256, 0, stream>>>(
        bufQ, 512, Wt2, b2, bufP, 256, 0, nullptr);
    // final: bufP @ Wlin2 + blin2 -> fp32 out (no relu)
    gemm_mfma<128, 64, 3, false, false><<<GB256, 256, 0, stream>>>(
        bufP, 256, Wtf, blin2, nullptr, 0, 0, out);
}

// Round 7
// 432.416 us; speedup vs baseline: 3.1483x; 1.1684x over previous
//
#include <hip/hip_runtime.h>
#include <cstddef>

static constexpr int NN = 100000;   // nodes
static constexpr int NE = 1600000;  // edges
static constexpr int NODE_SHIFT = 8;                       // 256 nodes per bucket
static constexpr int NB = (NN + 255) >> NODE_SHIFT;        // 391 buckets
static constexpr int CHUNK = 8192;                         // edges per binning block
static constexpr int NCH = (NE + CHUNK - 1) / CHUNK;       // 196 chunks

typedef short bf16x8 __attribute__((ext_vector_type(8)));
typedef float f32x4  __attribute__((ext_vector_type(4)));

__device__ __forceinline__ unsigned short f2bf(float f) {
    union { float f; unsigned u; } v; v.f = f;
    unsigned u = v.u + (0x7fffu + ((v.u >> 16) & 1u));   // RNE
    return (unsigned short)(u >> 16);
}
__device__ __forceinline__ float bf2f(unsigned short h) {
    union { unsigned u; float f; } v; v.u = ((unsigned)h) << 16;
    return v.f;
}

// accumulate 8 packed bf16 (uint4) into a[0..8): lo-half = <<16, hi-half = mask
__device__ __forceinline__ void acc8(const uint4& v, float* a) {
    union { unsigned u; float f; } t;
    t.u = v.x << 16;          a[0] += t.f;
    t.u = v.x & 0xffff0000u;  a[1] += t.f;
    t.u = v.y << 16;          a[2] += t.f;
    t.u = v.y & 0xffff0000u;  a[3] += t.f;
    t.u = v.z << 16;          a[4] += t.f;
    t.u = v.z & 0xffff0000u;  a[5] += t.f;
    t.u = v.w << 16;          a[6] += t.f;
    t.u = v.w & 0xffff0000u;  a[7] += t.f;
}

// ---------------- bucketed CSR construction ----------------

__global__ void zero_i32(int* p, int n) {
    int i = blockIdx.x * blockDim.x + threadIdx.x;
    if (i < n) p[i] = 0;
}

__global__ void bucket_count(const int* __restrict__ eidx, int* __restrict__ bcnt) {
    __shared__ int h[NB];
    for (int i = threadIdx.x; i < NB; i += 256) h[i] = 0;
    __syncthreads();
    int base = blockIdx.x * CHUNK;
    int end = min(base + CHUNK, NE);
    for (int e = base + threadIdx.x; e < end; e += 256)
        atomicAdd(&h[eidx[NE + e] >> NODE_SHIFT], 1);
    __syncthreads();
    for (int i = threadIdx.x; i < NB; i += 256)
        if (h[i]) atomicAdd(&bcnt[i], h[i]);
}

__global__ void bucket_scan(const int* __restrict__ bcnt, int* __restrict__ bbase,
                            int* __restrict__ bcur, int* __restrict__ row_ptr) {
    __shared__ int s[512];
    int t = threadIdx.x;
    int v = (t < NB) ? bcnt[t] : 0;
    s[t] = v; __syncthreads();
    for (int off = 1; off < 512; off <<= 1) {
        int x = (t >= off) ? s[t - off] : 0;
        __syncthreads();
        s[t] += x;
        __syncthreads();
    }
    if (t < NB) { int e = s[t] - v; bbase[t] = e; bcur[t] = e; }
    if (t == 0) { bbase[NB] = NE; row_ptr[NN] = NE; }
}

__global__ void bucket_scatter(const int* __restrict__ eidx, int* __restrict__ bcur,
                               uint2* __restrict__ pairs) {
    __shared__ int h[NB];
    __shared__ int cur[NB];
    __shared__ int off[NB];
    for (int i = threadIdx.x; i < NB; i += 256) { h[i] = 0; cur[i] = 0; }
    __syncthreads();
    int base = blockIdx.x * CHUNK;
    int end = min(base + CHUNK, NE);
    for (int e = base + threadIdx.x; e < end; e += 256)
        atomicAdd(&h[eidx[NE + e] >> NODE_SHIFT], 1);
    __syncthreads();
    for (int i = threadIdx.x; i < NB; i += 256)
        off[i] = h[i] ? atomicAdd(&bcur[i], h[i]) : 0;
    __syncthreads();
    for (int e = base + threadIdx.x; e < end; e += 256) {
        int d = eidx[NE + e], s = eidx[e];
        int b = d >> NODE_SHIFT;
        int p = atomicAdd(&cur[b], 1);
        pairs[off[b] + p] = make_uint2((unsigned)s, (unsigned)d);
    }
}

__launch_bounds__(256)
__global__ void bucket_csr(const uint2* __restrict__ pairs, const int* __restrict__ bbase,
                           int* __restrict__ row_ptr, int* __restrict__ ecsr) {
    __shared__ int hist[256];
    __shared__ int scn[256];
    __shared__ int cur[256];
    int b = blockIdx.x, t = threadIdx.x;
    int ebeg = bbase[b], eend = bbase[b + 1];
    int node0 = b << NODE_SHIFT;
    hist[t] = 0;
    __syncthreads();
    for (int e = ebeg + t; e < eend; e += 256)
        atomicAdd(&hist[pairs[e].y & 255u], 1);
    __syncthreads();
    int v = hist[t];
    scn[t] = v; __syncthreads();
    for (int off = 1; off < 256; off <<= 1) {
        int x = (t >= off) ? scn[t - off] : 0;
        __syncthreads();
        scn[t] += x;
        __syncthreads();
    }
    int excl = scn[t] - v;
    int node = node0 + t;
    if (node < NN) row_ptr[node] = ebeg + excl;
    cur[t] = excl;
    __syncthreads();
    for (int e = ebeg + t; e < eend; e += 256) {
        uint2 pr = pairs[e];
        int p = atomicAdd(&cur[pr.y & 255u], 1);
        ecsr[ebeg + p] = (int)pr.x;
    }
}

// ---------------- conversions ----------------

__global__ void convW(const float* __restrict__ W, unsigned short* __restrict__ Wt,
                      int K, int C, int wld, int kbase) {
    int t = blockIdx.x * blockDim.x + threadIdx.x;
    if (t >= K * C) return;
    int k = t / C, c = t % C;
    float v = W[t];
    unsigned short hi = f2bf(v);
    unsigned short lo = f2bf(v - bf2f(hi));
    size_t base = (size_t)c * wld + kbase;
    Wt[base + k] = hi;
    Wt[base + K + k] = lo;
    Wt[base + 2 * K + k] = hi;
}

// x [NN x 64] fp32 -> bufP cols [128..192)=hi, [192..256)=lo
__global__ void convX(const float* __restrict__ x, unsigned short* __restrict__ bufP) {
    int t = blockIdx.x * blockDim.x + threadIdx.x;
    if (t >= NN * 64) return;
    int r = t >> 6, c = t & 63;
    float v = x[t];
    unsigned short hi = f2bf(v);
    unsigned short lo = f2bf(v - bf2f(hi));
    bufP[(size_t)r * 256 + 128 + c] = hi;
    bufP[(size_t)r * 256 + 192 + c] = lo;
}

// ---------------- mean aggregation (hi-only gather, 16B/lane) ----------------
// Round-6 post-mortem: agg_pair was gather-byte-bound (376MB FETCH, 113us).
// Gather only the hi half (error contribution ~5e-4 after averaging, vs 6.6e-3
// threshold); 16B uint4 per lane; x4 edge unroll with independent accumulators.

// layer 1: gather bf16-hi x rows (bufP cols [128,192), 128B), write mean pair
// into bufP cols [0,64)=hi,[64,128)=lo.   TPN=8 lanes/node.
__launch_bounds__(256)
__global__ void agg_f32(const unsigned short* __restrict__ xp, const int* __restrict__ row_ptr,
                        const int* __restrict__ ecsr, unsigned short* __restrict__ outp) {
    constexpr int TPN = 8;
    int node = blockIdx.x * (256 / TPN) + threadIdx.x / TPN;
    int lane = threadIdx.x % TPN;
    if (node >= NN) return;
    int beg = row_ptr[node], end = row_ptr[node + 1];

    float a0[8] = {0,0,0,0,0,0,0,0}, a1[8] = {0,0,0,0,0,0,0,0};
    float a2[8] = {0,0,0,0,0,0,0,0}, a3[8] = {0,0,0,0,0,0,0,0};
    int i = beg;
    for (; i + 4 <= end; i += 4) {
        int s0 = ecsr[i], s1 = ecsr[i + 1], s2 = ecsr[i + 2], s3 = ecsr[i + 3];
        uint4 v0 = *(const uint4*)&xp[(size_t)s0 * 256 + 128 + lane * 8];
        uint4 v1 = *(const uint4*)&xp[(size_t)s1 * 256 + 128 + lane * 8];
        uint4 v2 = *(const uint4*)&xp[(size_t)s2 * 256 + 128 + lane * 8];
        uint4 v3 = *(const uint4*)&xp[(size_t)s3 * 256 + 128 + lane * 8];
        acc8(v0, a0); acc8(v1, a1); acc8(v2, a2); acc8(v3, a3);
    }
    for (; i < end; i++) {
        uint4 v0 = *(const uint4*)&xp[(size_t)ecsr[i] * 256 + 128 + lane * 8];
        acc8(v0, a0);
    }
    int deg = end - beg;
    float r = (deg > 0) ? 1.f / (float)deg : 0.f;
    ushort4 hi[2], lo[2];
    unsigned short* h = (unsigned short*)hi;
    unsigned short* l = (unsigned short*)lo;
#pragma unroll
    for (int j = 0; j < 8; j++) {
        float v = (a0[j] + a1[j] + a2[j] + a3[j]) * r;
        h[j] = f2bf(v);
        l[j] = f2bf(v - bf2f(h[j]));
    }
    unsigned short* orow = outp + (size_t)node * 256 + lane * 8;
    *(uint4*)orow = *(uint4*)hi;
    *(uint4*)(orow + 64) = *(uint4*)lo;
}

// layer 2: gather bf16-hi h rows (bufQ cols [256,384), 256B), write mean pair
// into bufQ cols [0,128)=hi,[128,256)=lo.  TPN=16 lanes/node.
__launch_bounds__(256)
__global__ void agg_pair(const unsigned short* __restrict__ hbuf, const int* __restrict__ row_ptr,
                         const int* __restrict__ ecsr, unsigned short* __restrict__ outp) {
    constexpr int TPN = 16;
    int node = blockIdx.x * (256 / TPN) + threadIdx.x / TPN;
    int lane = threadIdx.x % TPN;
    if (node >= NN) return;
    int beg = row_ptr[node], end = row_ptr[node + 1];

    float a0[8] = {0,0,0,0,0,0,0,0}, a1[8] = {0,0,0,0,0,0,0,0};
    float a2[8] = {0,0,0,0,0,0,0,0}, a3[8] = {0,0,0,0,0,0,0,0};
    int i = beg;
    for (; i + 4 <= end; i += 4) {
        int s0 = ecsr[i], s1 = ecsr[i + 1], s2 = ecsr[i + 2], s3 = ecsr[i + 3];
        uint4 v0 = *(const uint4*)&hbuf[(size_t)s0 * 512 + 256 + lane * 8];
        uint4 v1 = *(const uint4*)&hbuf[(size_t)s1 * 512 + 256 + lane * 8];
        uint4 v2 = *(const uint4*)&hbuf[(size_t)s2 * 512 + 256 + lane * 8];
        uint4 v3 = *(const uint4*)&hbuf[(size_t)s3 * 512 + 256 + lane * 8];
        acc8(v0, a0); acc8(v1, a1); acc8(v2, a2); acc8(v3, a3);
    }
    for (; i < end; i++) {
        uint4 v0 = *(const uint4*)&hbuf[(size_t)ecsr[i] * 512 + 256 + lane * 8];
        acc8(v0, a0);
    }
    int deg = end - beg;
    float r = (deg > 0) ? 1.f / (float)deg : 0.f;
    ushort4 hi[2], lo[2];
    unsigned short* h = (unsigned short*)hi;
    unsigned short* l = (unsigned short*)lo;
#pragma unroll
    for (int j = 0; j < 8; j++) {
        float v = (a0[j] + a1[j] + a2[j] + a3[j]) * r;
        h[j] = f2bf(v);
        l[j] = f2bf(v - bf2f(h[j]));
    }
    unsigned short* orow = outp + (size_t)node * 512 + lane * 8;
    *(uint4*)orow = *(uint4*)hi;
    *(uint4*)(orow + 128) = *(uint4*)lo;
}

// ---------------- MFMA GEMM over hi/lo segmented bf16 ----------------
template<int K, int C, int S, bool RELU, bool PAIR>
__launch_bounds__(256, 2)
__global__ void gemm_mfma(const unsigned short* __restrict__ A, int lda,
                          const unsigned short* __restrict__ Wt,
                          const float* __restrict__ bias,
                          unsigned short* __restrict__ outp, int old_, int obase,
                          float* __restrict__ outf) {
    constexpr int BM  = (C == 128) ? 128 : 256;
    constexpr int WLD = S * K;
    constexpr int NC  = S * K / 64;
    __shared__ unsigned short As[BM * 72];
    __shared__ unsigned short Ws[C * 72];

    const int tid  = threadIdx.x;
    const int lane = tid & 63, wave = tid >> 6;
    const int lrow = lane & 15, quad = lane >> 4;
    const int wrow0 = (C == 128) ? (wave >> 1) * 64 : wave * 64;
    const int wcol0 = (C == 128) ? (wave & 1) * 64 : 0;
    const int row0  = blockIdx.x * BM;

    f32x4 acc[4][4];
#pragma unroll
    for (int a = 0; a < 4; a++)
#pragma unroll
        for (int b = 0; b < 4; b++) acc[a][b] = (f32x4){0.f, 0.f, 0.f, 0.f};

#pragma unroll 1
    for (int cc = 0; cc < NC; ++cc) {
        int seg = (cc * 64) / K, inner = (cc * 64) % K;
        int acol = (seg / 3) * 2 * K + ((seg % 3) == 2 ? K : 0) + inner;
        for (int t = tid; t < BM * 8; t += 256) {
            int r = t >> 3, c8 = (t & 7) * 8;
            int gr = row0 + r;
            uint4 v = make_uint4(0u, 0u, 0u, 0u);
            if (gr < NN) v = *(const uint4*)&A[(size_t)gr * lda + acol + c8];
            *(uint4*)&As[r * 72 + c8] = v;
        }
        for (int t = tid; t < C * 8; t += 256) {
            int wr = t >> 3, c8 = (t & 7) * 8;
            *(uint4*)&Ws[wr * 72 + c8] = *(const uint4*)&Wt[(size_t)wr * WLD + cc * 64 + c8];
        }
        __syncthreads();
#pragma unroll
        for (int ks = 0; ks < 2; ++ks) {
            bf16x8 af[4], bfr[4];
#pragma unroll
            for (int rt = 0; rt < 4; rt++)
                af[rt] = *(const bf16x8*)&As[(wrow0 + rt * 16 + lrow) * 72 + ks * 32 + quad * 8];
#pragma unroll
            for (int ct = 0; ct < 4; ct++)
                bfr[ct] = *(const bf16x8*)&Ws[(wcol0 + ct * 16 + lrow) * 72 + ks * 32 + quad * 8];
#pragma unroll
            for (int rt = 0; rt < 4; rt++)
#pragma unroll
                for (int ct = 0; ct < 4; ct++)
                    acc[rt][ct] = __builtin_amdgcn_mfma_f32_16x16x32_bf16(
                        af[rt], bfr[ct], acc[rt][ct], 0, 0, 0);
        }
        __syncthreads();
    }

    float bcol[4];
#pragma unroll
    for (int ct = 0; ct < 4; ct++) bcol[ct] = bias[wcol0 + ct * 16 + lrow];
#pragma unroll
    for (int rt = 0; rt < 4; rt++) {
#pragma unroll
        for (int ct = 0; ct < 4; ct++) {
#pragma unroll
            for (int r = 0; r < 4; r++) {
                int grow = row0 + wrow0 + rt * 16 + quad * 4 + r;
                if (grow < NN) {
                    int col = wcol0 + ct * 16 + lrow;
                    float v = acc[rt][ct][r] + bcol[ct];
                    if (RELU) v = fmaxf(v, 0.f);
                    if (PAIR) {
                        unsigned short hi = f2bf(v);
                        unsigned short lo = f2bf(v - bf2f(hi));
                        outp[(size_t)grow * old_ + obase + col] = hi;
                        outp[(size_t)grow * old_ + obase + C + col] = lo;
                    } else {
                        outf[(size_t)grow * C + col] = v;
                    }
                }
            }
        }
    }
}

// ---------------- launch ----------------

extern "C" void kernel_launch(void* const* d_in, const int* in_sizes, int n_in,
                              void* d_out, int out_size, void* d_ws, size_t ws_size,
                              hipStream_t stream) {
    const float* x     = (const float*)d_in[0];
    const int*   eidx  = (const int*)d_in[1];
    const float* W1l   = (const float*)d_in[2];
    const float* b1    = (const float*)d_in[3];
    const float* W1r   = (const float*)d_in[4];
    const float* Wlin1 = (const float*)d_in[5];
    const float* blin1 = (const float*)d_in[6];
    const float* W2l   = (const float*)d_in[7];
    const float* b2    = (const float*)d_in[8];
    const float* W2r   = (const float*)d_in[9];
    const float* Wlin2 = (const float*)d_in[10];
    const float* blin2 = (const float*)d_in[11];
    float* out = (float*)d_out;
    (void)in_sizes; (void)n_in; (void)out_size; (void)ws_size;

    char* ws = (char*)d_ws;
    size_t off = 0;
    auto alloc = [&](size_t bytes) -> void* {
        void* p = ws + off;
        off = (off + bytes + 255) & ~(size_t)255;
        return p;
    };
    int* bcnt    = (int*)alloc((size_t)NB * 4);
    int* bbase   = (int*)alloc((size_t)(NB + 1) * 4);
    int* bcur    = (int*)alloc((size_t)NB * 4);
    int* row_ptr = (int*)alloc((size_t)(NN + 1) * 4);
    int* ecsr    = (int*)alloc((size_t)NE * 4);
    uint2* pairs = (uint2*)alloc((size_t)NE * 8);
    unsigned short* Wt1  = (unsigned short*)alloc((size_t)128 * 384 * 2);
    unsigned short* Wtl1 = (unsigned short*)alloc((size_t)128 * 384 * 2);
    unsigned short* Wt2  = (unsigned short*)alloc((size_t)128 * 768 * 2);
    unsigned short* Wtf  = (unsigned short*)alloc((size_t)64  * 384 * 2);
    unsigned short* bufP = (unsigned short*)alloc((size_t)NN * 256 * 2);  // 51.2 MB
    unsigned short* bufQ = (unsigned short*)alloc((size_t)NN * 512 * 2);  // 102.4 MB

    // bucketed CSR build
    zero_i32<<<(NB + 255) / 256, 256, 0, stream>>>(bcnt, NB);
    bucket_count<<<NCH, 256, 0, stream>>>(eidx, bcnt);
    bucket_scan<<<1, 512, 0, stream>>>(bcnt, bbase, bcur, row_ptr);
    bucket_scatter<<<NCH, 256, 0, stream>>>(eidx, bcur, pairs);
    bucket_csr<<<NB, 256, 0, stream>>>(pairs, bbase, row_ptr, ecsr);

    // weight conversions (tiny)
    convW<<<32, 256, 0, stream>>>(W1l,   Wt1,  64, 128, 384, 0);
    convW<<<32, 256, 0, stream>>>(W1r,   Wt1,  64, 128, 384, 192);
    convW<<<64, 256, 0, stream>>>(Wlin1, Wtl1, 128, 128, 384, 0);
    convW<<<64, 256, 0, stream>>>(W2l,   Wt2,  128, 128, 768, 0);
    convW<<<64, 256, 0, stream>>>(W2r,   Wt2,  128, 128, 768, 384);
    convW<<<32, 256, 0, stream>>>(Wlin2, Wtf,  128, 64, 384, 0);

    // x -> bf16 pair (bufP cols 128..255); mean1 (from x-hi) -> bufP cols 0..127
    convX<<<(NN * 64 + 255) / 256, 256, 0, stream>>>(x, bufP);
    agg_f32<<<(NN + 31) / 32, 256, 0, stream>>>(bufP, row_ptr, ecsr, bufP);

    const int GB128 = (NN + 127) / 128;
    const int GB256 = (NN + 255) / 256;

    // L1 SAGE: bufP[mean|x] @ [W1l;W1r] -> h1 pair into bufQ cols 0..255
    gemm_mfma<64, 128, 6, true, true><<<GB128, 256, 0, stream>>>(
        bufP, 256, Wt1, b1, bufQ, 512, 0, nullptr);
    // lin1: bufQ cols 0..255 @ Wlin1 -> h pair into bufQ cols 256..511
    gemm_mfma<128, 128, 3, true, true><<<GB128, 256, 0, stream>>>(
        bufQ, 512, Wtl1, blin1, bufQ, 512, 256, nullptr);
    // mean2 from h-hi -> bufQ cols 0..255
    agg_pair<<<(NN + 15) / 16, 256, 0, stream>>>(bufQ, row_ptr, ecsr, bufQ);
    // L2 SAGE: bufQ[mean2|h] @ [W2l;W2r] -> h2 pair into bufP
    gemm_mfma<128, 128, 6, true, true><<<GB128, 256, 0, stream>>>(
        bufQ, 512, Wt2, b2, bufP, 256, 0, nullptr);
    // final: bufP @ Wlin2 + blin2 -> fp32 out (no relu)
    gemm_mfma<128, 64, 3, false, false><<<GB256, 256, 0, stream>>>(
        bufP, 256, Wtf, blin2, nullptr, 0, 0, out);
}